// Round 1
// baseline (878.987 us; speedup 1.0000x reference)
//
#include <hip/hip_runtime.h>

// GraphSAGE (mean) x3 + per-graph mean pool, MI355X.
// Strategy: build CSR (dst -> list of src) once per call, then per layer run a
// fused gather+dual-matmul kernel (wave-per-node, W in registers, readlane
// broadcast), then pooled mean via sorted-batch binary search.

#define DD 64

__global__ void count_deg(const int* __restrict__ dst, int* __restrict__ deg, int E) {
    int e = blockIdx.x * 256 + threadIdx.x;
    if (e < E) atomicAdd(&deg[dst[e]], 1);
}

// inclusive scan of deg within 1024-chunks; chunk totals to bsum
__global__ void scan1(const int* __restrict__ deg, int* __restrict__ offs,
                      int* __restrict__ bsum, int n) {
    __shared__ int s[1024];
    int t = threadIdx.x;
    int i = blockIdx.x * 1024 + t;
    int v = (i < n) ? deg[i] : 0;
    s[t] = v;
    __syncthreads();
    for (int o = 1; o < 1024; o <<= 1) {
        int a = (t >= o) ? s[t - o] : 0;
        __syncthreads();
        s[t] += a;
        __syncthreads();
    }
    if (i < n) offs[i + 1] = s[t];
    if (t == 1023) bsum[blockIdx.x] = s[t];
    if (blockIdx.x == 0 && t == 0) offs[0] = 0;
}

// exclusive scan of block sums (single block, supports up to 1024 chunks)
__global__ void scan2(int* __restrict__ bsum, int nb) {
    __shared__ int s[1024];
    int t = threadIdx.x;
    s[t] = (t < nb) ? bsum[t] : 0;
    __syncthreads();
    for (int o = 1; o < 1024; o <<= 1) {
        int a = (t >= o) ? s[t - o] : 0;
        __syncthreads();
        s[t] += a;
        __syncthreads();
    }
    int ex = (t > 0) ? s[t - 1] : 0;
    if (t < nb) bsum[t] = ex;
}

__global__ void scan3(int* __restrict__ offs, const int* __restrict__ bsum, int n) {
    int i = blockIdx.x * 1024 + threadIdx.x;
    if (i < n) offs[i + 1] += bsum[blockIdx.x];
}

__global__ void fill_adj(const int* __restrict__ src, const int* __restrict__ dst,
                         int* __restrict__ cursor, int* __restrict__ adj, int E) {
    int e = blockIdx.x * 256 + threadIdx.x;
    if (e < E) {
        int pos = atomicAdd(&cursor[dst[e]], 1);
        adj[pos] = src[e];
    }
}

// One wave per node (lane = feature dim). Grid-stride over nodes so the
// 128 W-column registers are loaded once per wave lifetime.
// out[n][d] = bias[d] + sum_k agg[n][k]*Wl[k][d] + sum_k x[n][k]*Wr[k][d]
__global__ __launch_bounds__(256) void sage_layer(
    const float* __restrict__ xin, float* __restrict__ xout,
    const int* __restrict__ offs, const int* __restrict__ adj,
    const float* __restrict__ Wl, const float* __restrict__ bl,
    const float* __restrict__ Wr, int n) {
    const int lane = threadIdx.x & 63;
    const int wid  = (int)((blockIdx.x * blockDim.x + threadIdx.x) >> 6);
    const int nw   = (int)((gridDim.x * blockDim.x) >> 6);

    float wl[DD], wr[DD];
#pragma unroll
    for (int k = 0; k < DD; ++k) {
        wl[k] = Wl[k * DD + lane];   // column `lane` of Wl
        wr[k] = Wr[k * DD + lane];
    }
    const float bias = bl[lane];

    for (int nd = wid; nd < n; nd += nw) {
        const float xr = xin[(size_t)nd * DD + lane];
        const int s = offs[nd];
        const int e = offs[nd + 1];
        float g = 0.f;
        for (int j = s; j < e; ++j) {
            g += xin[(size_t)adj[j] * DD + lane];   // coalesced 256B row read
        }
        const int cnt = e - s;
        g *= (cnt > 0) ? (1.0f / (float)cnt) : 1.0f;

        float acc = bias;
#pragma unroll
        for (int k = 0; k < DD; ++k) {
            // wave-uniform broadcast of element k via readlane (constant lane idx)
            const float gk = __int_as_float(__builtin_amdgcn_readlane(__float_as_int(g),  k));
            const float xk = __int_as_float(__builtin_amdgcn_readlane(__float_as_int(xr), k));
            acc += gk * wl[k] + xk * wr[k];
        }
        xout[(size_t)nd * DD + lane] = acc;
    }
}

// batch is sorted: block g finds its node range via binary search, mean-reduces.
__global__ void pool_kernel(const float* __restrict__ x, const int* __restrict__ batch,
                            float* __restrict__ out, int n) {
    const int g = blockIdx.x;
    int lo = 0, hi = n;
    while (lo < hi) { int m = (lo + hi) >> 1; if (batch[m] < g) lo = m + 1; else hi = m; }
    const int start = lo;
    lo = 0; hi = n;
    while (lo < hi) { int m = (lo + hi) >> 1; if (batch[m] < g + 1) lo = m + 1; else hi = m; }
    const int end = lo;

    const int lane = threadIdx.x & 63;
    const int w    = threadIdx.x >> 6;
    float acc = 0.f;
    for (int nd = start + w; nd < end; nd += 4) acc += x[(size_t)nd * DD + lane];

    __shared__ float red[4][DD];
    red[w][lane] = acc;
    __syncthreads();
    if (threadIdx.x < DD) {
        float s = red[0][threadIdx.x] + red[1][threadIdx.x] +
                  red[2][threadIdx.x] + red[3][threadIdx.x];
        int c = end - start;
        out[(size_t)g * DD + threadIdx.x] = s / (float)((c > 0) ? c : 1);
    }
}

extern "C" void kernel_launch(void* const* d_in, const int* in_sizes, int n_in,
                              void* d_out, int out_size, void* d_ws, size_t ws_size,
                              hipStream_t stream) {
    const float* x     = (const float*)d_in[0];
    const int*   ei    = (const int*)d_in[1];
    const int*   batch = (const int*)d_in[2];
    const float* Wl    = (const float*)d_in[3];
    const float* bl    = (const float*)d_in[4];
    const float* Wr    = (const float*)d_in[5];

    const int N = in_sizes[0] / DD;
    const int E = in_sizes[1] / 2;
    const int L = in_sizes[3] / (DD * DD);
    const int G = out_size / DD;

    const int* src = ei;        // edge_index[0]
    const int* dst = ei + E;    // edge_index[1]

    char* ws = (char*)d_ws;
    size_t off = 0;
    auto alloc = [&](size_t bytes) -> char* {
        char* p = ws + off;
        off += (bytes + 255) & ~(size_t)255;
        return p;
    };
    int*   deg    = (int*)alloc((size_t)N * 4);
    int*   offs   = (int*)alloc((size_t)(N + 1) * 4);
    int*   cursor = (int*)alloc((size_t)N * 4);
    int*   adj    = (int*)alloc((size_t)E * 4);
    int*   bsum   = (int*)alloc(1024 * 4);
    float* b0     = (float*)alloc((size_t)N * DD * 4);
    float* b1     = (float*)alloc((size_t)N * DD * 4);

    // ---- CSR build (same graph reused by all 3 layers) ----
    hipMemsetAsync(deg, 0, (size_t)N * 4, stream);
    count_deg<<<(E + 255) / 256, 256, 0, stream>>>(dst, deg, E);
    const int nb = (N + 1023) / 1024;
    scan1<<<nb, 1024, 0, stream>>>(deg, offs, bsum, N);
    scan2<<<1, 1024, 0, stream>>>(bsum, nb);
    scan3<<<nb, 1024, 0, stream>>>(offs, bsum, N);
    hipMemcpyAsync(cursor, offs, (size_t)N * 4, hipMemcpyDeviceToDevice, stream);
    fill_adj<<<(E + 255) / 256, 256, 0, stream>>>(src, dst, cursor, adj, E);

    // ---- layers (ping-pong) ----
    const float* cur = x;
    float* bufs[2] = {b0, b1};
    for (int l = 0; l < L; ++l) {
        float* outb = bufs[l & 1];
        sage_layer<<<768, 256, 0, stream>>>(cur, outb, offs, adj,
                                            Wl + (size_t)l * DD * DD,
                                            bl + (size_t)l * DD,
                                            Wr + (size_t)l * DD * DD, N);
        cur = outb;
    }

    // ---- per-graph mean pool ----
    pool_kernel<<<G, 256, 0, stream>>>(cur, batch, (float*)d_out, N);
}

// Round 2
// 628.077 us; speedup vs baseline: 1.3995x; 1.3995x over previous
//
#include <hip/hip_runtime.h>

// GraphSAGE (mean) x3 + per-graph mean pool, MI355X.
// R2: split fused layer into (a) latency-optimized gather-mean kernel at full
// occupancy, (b) VALU-optimized dual-GEMM with W pinned in VGPRs via asm.

#define DD 64

__global__ void count_deg(const int* __restrict__ dst, int* __restrict__ deg, int E) {
    int e = blockIdx.x * 256 + threadIdx.x;
    if (e < E) atomicAdd(&deg[dst[e]], 1);
}

// inclusive scan of deg within 1024-chunks; chunk totals to bsum
__global__ void scan1(const int* __restrict__ deg, int* __restrict__ offs,
                      int* __restrict__ bsum, int n) {
    __shared__ int s[1024];
    int t = threadIdx.x;
    int i = blockIdx.x * 1024 + t;
    int v = (i < n) ? deg[i] : 0;
    s[t] = v;
    __syncthreads();
    for (int o = 1; o < 1024; o <<= 1) {
        int a = (t >= o) ? s[t - o] : 0;
        __syncthreads();
        s[t] += a;
        __syncthreads();
    }
    if (i < n) offs[i + 1] = s[t];
    if (t == 1023) bsum[blockIdx.x] = s[t];
    if (blockIdx.x == 0 && t == 0) offs[0] = 0;
}

__global__ void scan2(int* __restrict__ bsum, int nb) {
    __shared__ int s[1024];
    int t = threadIdx.x;
    s[t] = (t < nb) ? bsum[t] : 0;
    __syncthreads();
    for (int o = 1; o < 1024; o <<= 1) {
        int a = (t >= o) ? s[t - o] : 0;
        __syncthreads();
        s[t] += a;
        __syncthreads();
    }
    int ex = (t > 0) ? s[t - 1] : 0;
    if (t < nb) bsum[t] = ex;
}

__global__ void scan3(int* __restrict__ offs, const int* __restrict__ bsum, int n) {
    int i = blockIdx.x * 1024 + threadIdx.x;
    if (i < n) offs[i + 1] += bsum[blockIdx.x];
}

__global__ void fill_adj(const int* __restrict__ src, const int* __restrict__ dst,
                         int* __restrict__ cursor, int* __restrict__ adj, int E) {
    int e = blockIdx.x * 256 + threadIdx.x;
    if (e < E) {
        int pos = atomicAdd(&cursor[dst[e]], 1);
        adj[pos] = src[e];
    }
}

// ---- gather-mean: 16 threads per node, each owns a float4 chunk of the row.
// 4-deep unrolled edge loop with independent accumulators for MLP.
__global__ __launch_bounds__(256) void aggregate(
    const float* __restrict__ xin, float* __restrict__ agg,
    const int* __restrict__ offs, const int* __restrict__ adj, int n) {
    const int t  = blockIdx.x * 256 + threadIdx.x;
    const int nd = t >> 4;
    const int c  = (t & 15) * 4;
    if (nd >= n) return;

    const int s = offs[nd];
    const int e = offs[nd + 1];

    float4 a0 = {0.f, 0.f, 0.f, 0.f};
    float4 a1 = {0.f, 0.f, 0.f, 0.f};
    float4 a2 = {0.f, 0.f, 0.f, 0.f};
    float4 a3 = {0.f, 0.f, 0.f, 0.f};

    int j = s;
    for (; j + 4 <= e; j += 4) {
        const int i0 = adj[j], i1 = adj[j + 1], i2 = adj[j + 2], i3 = adj[j + 3];
        const float4 v0 = *reinterpret_cast<const float4*>(xin + (size_t)i0 * DD + c);
        const float4 v1 = *reinterpret_cast<const float4*>(xin + (size_t)i1 * DD + c);
        const float4 v2 = *reinterpret_cast<const float4*>(xin + (size_t)i2 * DD + c);
        const float4 v3 = *reinterpret_cast<const float4*>(xin + (size_t)i3 * DD + c);
        a0.x += v0.x; a0.y += v0.y; a0.z += v0.z; a0.w += v0.w;
        a1.x += v1.x; a1.y += v1.y; a1.z += v1.z; a1.w += v1.w;
        a2.x += v2.x; a2.y += v2.y; a2.z += v2.z; a2.w += v2.w;
        a3.x += v3.x; a3.y += v3.y; a3.z += v3.z; a3.w += v3.w;
    }
    for (; j < e; ++j) {
        const float4 v = *reinterpret_cast<const float4*>(xin + (size_t)adj[j] * DD + c);
        a0.x += v.x; a0.y += v.y; a0.z += v.z; a0.w += v.w;
    }

    const int deg = e - s;
    const float inv = (deg > 0) ? (1.0f / (float)deg) : 1.0f;
    float4 r;
    r.x = (a0.x + a1.x + a2.x + a3.x) * inv;
    r.y = (a0.y + a1.y + a2.y + a3.y) * inv;
    r.z = (a0.z + a1.z + a2.z + a3.z) * inv;
    r.w = (a0.w + a1.w + a2.w + a3.w) * inv;
    *reinterpret_cast<float4*>(agg + (size_t)nd * DD + c) = r;
}

// ---- out[n][d] = b[d] + sum_k g[n][k]*Wl[k][d] + sum_k x[n][k]*Wr[k][d]
// lane = d. W columns pinned in VGPRs (asm keep-alive prevents remat/sink).
__global__ __launch_bounds__(256, 1) void dual_gemm(
    const float* __restrict__ g, const float* __restrict__ x,
    float* __restrict__ out, const float* __restrict__ Wl,
    const float* __restrict__ bl, const float* __restrict__ Wr, int n) {
    const int lane = threadIdx.x & 63;
    const int wid  = (int)((blockIdx.x * blockDim.x + threadIdx.x) >> 6);
    const int nw   = (int)((gridDim.x * blockDim.x) >> 6);

    float wl[DD], wr[DD];
#pragma unroll
    for (int k = 0; k < DD; ++k) {
        wl[k] = Wl[k * DD + lane];
        wr[k] = Wr[k * DD + lane];
        asm volatile("" : "+v"(wl[k]), "+v"(wr[k]));   // pin in VGPRs
    }
    const float bias = bl[lane];

    for (int nd = wid; nd < n; nd += nw) {
        const float gv = g[(size_t)nd * DD + lane];
        const float xv = x[(size_t)nd * DD + lane];
        float acc = bias;
#pragma unroll
        for (int k = 0; k < DD; ++k) {
            const float gk = __int_as_float(__builtin_amdgcn_readlane(__float_as_int(gv), k));
            const float xk = __int_as_float(__builtin_amdgcn_readlane(__float_as_int(xv), k));
            acc += gk * wl[k] + xk * wr[k];
        }
        out[(size_t)nd * DD + lane] = acc;
    }
}

// batch is sorted: block g finds its node range via binary search, mean-reduces.
__global__ void pool_kernel(const float* __restrict__ x, const int* __restrict__ batch,
                            float* __restrict__ out, int n) {
    const int g = blockIdx.x;
    int lo = 0, hi = n;
    while (lo < hi) { int m = (lo + hi) >> 1; if (batch[m] < g) lo = m + 1; else hi = m; }
    const int start = lo;
    lo = 0; hi = n;
    while (lo < hi) { int m = (lo + hi) >> 1; if (batch[m] < g + 1) lo = m + 1; else hi = m; }
    const int end = lo;

    const int lane = threadIdx.x & 63;
    const int w    = threadIdx.x >> 6;
    float acc = 0.f;
    for (int nd = start + w; nd < end; nd += 4) acc += x[(size_t)nd * DD + lane];

    __shared__ float red[4][DD];
    red[w][lane] = acc;
    __syncthreads();
    if (threadIdx.x < DD) {
        float s = red[0][threadIdx.x] + red[1][threadIdx.x] +
                  red[2][threadIdx.x] + red[3][threadIdx.x];
        int c = end - start;
        out[(size_t)g * DD + threadIdx.x] = s / (float)((c > 0) ? c : 1);
    }
}

extern "C" void kernel_launch(void* const* d_in, const int* in_sizes, int n_in,
                              void* d_out, int out_size, void* d_ws, size_t ws_size,
                              hipStream_t stream) {
    const float* x     = (const float*)d_in[0];
    const int*   ei    = (const int*)d_in[1];
    const int*   batch = (const int*)d_in[2];
    const float* Wl    = (const float*)d_in[3];
    const float* bl    = (const float*)d_in[4];
    const float* Wr    = (const float*)d_in[5];

    const int N = in_sizes[0] / DD;
    const int E = in_sizes[1] / 2;
    const int L = in_sizes[3] / (DD * DD);
    const int G = out_size / DD;

    const int* src = ei;        // edge_index[0]
    const int* dst = ei + E;    // edge_index[1]

    char* ws = (char*)d_ws;
    size_t off = 0;
    auto alloc = [&](size_t bytes) -> char* {
        char* p = ws + off;
        off += (bytes + 255) & ~(size_t)255;
        return p;
    };
    int*   deg    = (int*)alloc((size_t)N * 4);
    int*   offs   = (int*)alloc((size_t)(N + 1) * 4);
    int*   cursor = (int*)alloc((size_t)N * 4);
    int*   adj    = (int*)alloc((size_t)E * 4);
    int*   bsum   = (int*)alloc(1024 * 4);
    float* b0     = (float*)alloc((size_t)N * DD * 4);
    float* b1     = (float*)alloc((size_t)N * DD * 4);
    float* aggbuf = (float*)alloc((size_t)N * DD * 4);

    // ---- CSR build (graph reused by all layers) ----
    hipMemsetAsync(deg, 0, (size_t)N * 4, stream);
    count_deg<<<(E + 255) / 256, 256, 0, stream>>>(dst, deg, E);
    const int nb = (N + 1023) / 1024;
    scan1<<<nb, 1024, 0, stream>>>(deg, offs, bsum, N);
    scan2<<<1, 1024, 0, stream>>>(bsum, nb);
    scan3<<<nb, 1024, 0, stream>>>(offs, bsum, N);
    hipMemcpyAsync(cursor, offs, (size_t)N * 4, hipMemcpyDeviceToDevice, stream);
    fill_adj<<<(E + 255) / 256, 256, 0, stream>>>(src, dst, cursor, adj, E);

    // ---- layers (ping-pong) ----
    const int agg_blocks = (N * 16 + 255) / 256;
    const float* cur = x;
    float* bufs[2] = {b0, b1};
    for (int l = 0; l < L; ++l) {
        float* outb = bufs[l & 1];
        aggregate<<<agg_blocks, 256, 0, stream>>>(cur, aggbuf, offs, adj, N);
        dual_gemm<<<768, 256, 0, stream>>>(aggbuf, cur, outb,
                                           Wl + (size_t)l * DD * DD,
                                           bl + (size_t)l * DD,
                                           Wr + (size_t)l * DD * DD, N);
        cur = outb;
    }

    // ---- per-graph mean pool ----
    pool_kernel<<<G, 256, 0, stream>>>(cur, batch, (float*)d_out, N);
}

// Round 3
// 353.761 us; speedup vs baseline: 2.4847x; 1.7754x over previous
//
#include <hip/hip_runtime.h>

// GraphSAGE (mean) x3 + per-graph mean pool, MI355X.
// R3: (a) pool -> two-stage grid-wide partial sums + finalize (was 106us @ 64
// blocks); (b) dual_gemm -> MFMA 16x16x32 bf16 with bf16x3 split (fp32-grade
// accuracy), W pre-packed into fragment layout, B-frags VGPR-resident.

#define DD 64

typedef __attribute__((ext_vector_type(8))) short short8;   // 8 bf16 (4 VGPRs)
typedef __attribute__((ext_vector_type(4))) float f32x4;    // MFMA accumulator

__device__ inline short8 pack4(unsigned a, unsigned b, unsigned c, unsigned d) {
    union { uint4 u; short8 s; } un;
    un.u = make_uint4(a, b, c, d);
    return un.s;
}

// ---------------- CSR build ----------------
__global__ void count_deg(const int* __restrict__ dst, int* __restrict__ deg, int E) {
    int e = blockIdx.x * 256 + threadIdx.x;
    if (e < E) atomicAdd(&deg[dst[e]], 1);
}

__global__ void scan1(const int* __restrict__ deg, int* __restrict__ offs,
                      int* __restrict__ bsum, int n) {
    __shared__ int s[1024];
    int t = threadIdx.x;
    int i = blockIdx.x * 1024 + t;
    int v = (i < n) ? deg[i] : 0;
    s[t] = v;
    __syncthreads();
    for (int o = 1; o < 1024; o <<= 1) {
        int a = (t >= o) ? s[t - o] : 0;
        __syncthreads();
        s[t] += a;
        __syncthreads();
    }
    if (i < n) offs[i + 1] = s[t];
    if (t == 1023) bsum[blockIdx.x] = s[t];
    if (blockIdx.x == 0 && t == 0) offs[0] = 0;
}

__global__ void scan2(int* __restrict__ bsum, int nb) {
    __shared__ int s[1024];
    int t = threadIdx.x;
    s[t] = (t < nb) ? bsum[t] : 0;
    __syncthreads();
    for (int o = 1; o < 1024; o <<= 1) {
        int a = (t >= o) ? s[t - o] : 0;
        __syncthreads();
        s[t] += a;
        __syncthreads();
    }
    int ex = (t > 0) ? s[t - 1] : 0;
    if (t < nb) bsum[t] = ex;
}

__global__ void scan3(int* __restrict__ offs, const int* __restrict__ bsum, int n) {
    int i = blockIdx.x * 1024 + threadIdx.x;
    if (i < n) offs[i + 1] += bsum[blockIdx.x];
}

__global__ void fill_adj(const int* __restrict__ src, const int* __restrict__ dst,
                         int* __restrict__ cursor, int* __restrict__ adj, int E) {
    int e = blockIdx.x * 256 + threadIdx.x;
    if (e < E) {
        int pos = atomicAdd(&cursor[dst[e]], 1);
        adj[pos] = src[e];
    }
}

// ---------------- gather-mean (16 threads/node, float4 chunks) ----------------
__global__ __launch_bounds__(256) void aggregate(
    const float* __restrict__ xin, float* __restrict__ agg,
    const int* __restrict__ offs, const int* __restrict__ adj, int n) {
    const int t  = blockIdx.x * 256 + threadIdx.x;
    const int nd = t >> 4;
    const int c  = (t & 15) * 4;
    if (nd >= n) return;

    const int s = offs[nd];
    const int e = offs[nd + 1];

    float4 a0 = {0.f, 0.f, 0.f, 0.f};
    float4 a1 = {0.f, 0.f, 0.f, 0.f};
    float4 a2 = {0.f, 0.f, 0.f, 0.f};
    float4 a3 = {0.f, 0.f, 0.f, 0.f};

    int j = s;
    for (; j + 4 <= e; j += 4) {
        const int i0 = adj[j], i1 = adj[j + 1], i2 = adj[j + 2], i3 = adj[j + 3];
        const float4 v0 = *reinterpret_cast<const float4*>(xin + (size_t)i0 * DD + c);
        const float4 v1 = *reinterpret_cast<const float4*>(xin + (size_t)i1 * DD + c);
        const float4 v2 = *reinterpret_cast<const float4*>(xin + (size_t)i2 * DD + c);
        const float4 v3 = *reinterpret_cast<const float4*>(xin + (size_t)i3 * DD + c);
        a0.x += v0.x; a0.y += v0.y; a0.z += v0.z; a0.w += v0.w;
        a1.x += v1.x; a1.y += v1.y; a1.z += v1.z; a1.w += v1.w;
        a2.x += v2.x; a2.y += v2.y; a2.z += v2.z; a2.w += v2.w;
        a3.x += v3.x; a3.y += v3.y; a3.z += v3.z; a3.w += v3.w;
    }
    for (; j < e; ++j) {
        const float4 v = *reinterpret_cast<const float4*>(xin + (size_t)adj[j] * DD + c);
        a0.x += v.x; a0.y += v.y; a0.z += v.z; a0.w += v.w;
    }

    const int deg = e - s;
    const float inv = (deg > 0) ? (1.0f / (float)deg) : 1.0f;
    float4 r;
    r.x = (a0.x + a1.x + a2.x + a3.x) * inv;
    r.y = (a0.y + a1.y + a2.y + a3.y) * inv;
    r.z = (a0.z + a1.z + a2.z + a3.z) * inv;
    r.w = (a0.w + a1.w + a2.w + a3.w) * inv;
    *reinterpret_cast<float4*>(agg + (size_t)nd * DD + c) = r;
}

// ---------------- W pre-pack into MFMA B-fragment layout, bf16 hi/lo ----------
// B(global) = [Wl ; Wr]  (128 x 64). Frag (ks,nt): lane l holds
// B[ks*32 + (l>>4)*8 + s][nt*16 + (l&15)], s=0..7, packed 2 bf16/dword.
// Bp layout: [layer][hi/lo][fid=ks*4+nt][lane][4 dwords]
__global__ void pack_B(const float* __restrict__ Wl, const float* __restrict__ Wr,
                       unsigned* __restrict__ Bp, int L) {
    int t = blockIdx.x * 256 + threadIdx.x;
    int wv = t >> 6, lane = t & 63;
    if (wv >= L * 16) return;
    int layer = wv >> 4;
    int fid = wv & 15;
    int ks = fid >> 2, nt = fid & 3;
    int j = nt * 16 + (lane & 15);
    int kb = ks * 32 + (lane >> 4) * 8;
    const float* wl = Wl + (size_t)layer * DD * DD;
    const float* wr = Wr + (size_t)layer * DD * DD;
    unsigned hi[8], lo[8];
#pragma unroll
    for (int s = 0; s < 8; ++s) {
        int k = kb + s;
        float v = (k < DD) ? wl[k * DD + j] : wr[(k - DD) * DD + j];
        unsigned u = __float_as_uint(v);
        unsigned h = u & 0xFFFF0000u;
        hi[s] = h;
        float lf = v - __uint_as_float(h);         // exact residual
        lo[s] = __float_as_uint(lf) & 0xFFFF0000u;
    }
    size_t base_hi = ((size_t)(layer * 2 + 0) * 16 + fid) * 64 + lane;
    size_t base_lo = ((size_t)(layer * 2 + 1) * 16 + fid) * 64 + lane;
#pragma unroll
    for (int p = 0; p < 4; ++p) {
        Bp[base_hi * 4 + p] = (hi[2 * p] >> 16) | hi[2 * p + 1];
        Bp[base_lo * 4 + p] = (lo[2 * p] >> 16) | lo[2 * p + 1];
    }
}

// ---------------- layer GEMM: out = bias + [agg|x] @ [Wl;Wr], MFMA bf16x3 ----
// Wave computes a 16-node x 64-dim tile. B-frags VGPR-resident, grid-stride.
__global__ __launch_bounds__(256, 2) void mfma_gemm(
    const float* __restrict__ g, const float* __restrict__ x,
    float* __restrict__ out, const unsigned* __restrict__ Bp,
    const float* __restrict__ bias, int n) {
    const int lane = threadIdx.x & 63;
    const int wv   = (int)((blockIdx.x * 256 + threadIdx.x) >> 6);
    const int nwv  = (int)((gridDim.x * 256) >> 6);

    short8 Bh[4][4], Bl[4][4];
#pragma unroll
    for (int ks = 0; ks < 4; ++ks)
#pragma unroll
        for (int nt = 0; nt < 4; ++nt) {
            int fid = ks * 4 + nt;
            const uint4 h = *reinterpret_cast<const uint4*>(Bp + ((size_t)fid * 64 + lane) * 4);
            const uint4 l = *reinterpret_cast<const uint4*>(Bp + ((size_t)(16 + fid) * 64 + lane) * 4);
            Bh[ks][nt] = pack4(h.x, h.y, h.z, h.w);
            Bl[ks][nt] = pack4(l.x, l.y, l.z, l.w);
        }

    float bv[4];
#pragma unroll
    for (int nt = 0; nt < 4; ++nt) bv[nt] = bias[nt * 16 + (lane & 15)];

    const int ntiles = (n + 15) >> 4;
    for (int tile = wv; tile < ntiles; tile += nwv) {
        const int row = tile * 16 + (lane & 15);
        const bool ok = row < n;
        const float* grow = g + (size_t)row * DD + (lane >> 4) * 8;
        const float* xrow = x + (size_t)row * DD + (lane >> 4) * 8;

        f32x4 acc[4];
#pragma unroll
        for (int nt = 0; nt < 4; ++nt) acc[nt] = (f32x4){bv[nt], bv[nt], bv[nt], bv[nt]};

#pragma unroll
        for (int ks = 0; ks < 4; ++ks) {
            const float* base = ((ks < 2) ? grow : xrow) + (ks & 1) * 32;
            f32x4 v0 = ok ? *reinterpret_cast<const f32x4*>(base)
                          : (f32x4){0.f, 0.f, 0.f, 0.f};
            f32x4 v1 = ok ? *reinterpret_cast<const f32x4*>(base + 4)
                          : (f32x4){0.f, 0.f, 0.f, 0.f};
            float vv[8] = {v0[0], v0[1], v0[2], v0[3], v1[0], v1[1], v1[2], v1[3]};
            unsigned hu[4], lu[4];
#pragma unroll
            for (int p = 0; p < 4; ++p) {
                unsigned ua = __float_as_uint(vv[2 * p]);
                unsigned ub = __float_as_uint(vv[2 * p + 1]);
                unsigned ha = ua & 0xFFFF0000u, hb = ub & 0xFFFF0000u;
                hu[p] = (ha >> 16) | hb;
                float la = vv[2 * p]     - __uint_as_float(ha);
                float lb = vv[2 * p + 1] - __uint_as_float(hb);
                lu[p] = ((__float_as_uint(la) & 0xFFFF0000u) >> 16) |
                        (__float_as_uint(lb) & 0xFFFF0000u);
            }
            const short8 Ah = pack4(hu[0], hu[1], hu[2], hu[3]);
            const short8 Al = pack4(lu[0], lu[1], lu[2], lu[3]);
#pragma unroll
            for (int nt = 0; nt < 4; ++nt) {
                acc[nt] = __builtin_amdgcn_mfma_f32_16x16x32_bf16(Ah, Bh[ks][nt], acc[nt], 0, 0, 0);
                acc[nt] = __builtin_amdgcn_mfma_f32_16x16x32_bf16(Al, Bh[ks][nt], acc[nt], 0, 0, 0);
                acc[nt] = __builtin_amdgcn_mfma_f32_16x16x32_bf16(Ah, Bl[ks][nt], acc[nt], 0, 0, 0);
            }
        }

        // C/D layout (verified): col = lane&15, row = (lane>>4)*4 + reg
        const int r0 = tile * 16 + (lane >> 4) * 4;
#pragma unroll
        for (int r = 0; r < 4; ++r) {
            const int rr = r0 + r;
            if (rr < n) {
#pragma unroll
                for (int nt = 0; nt < 4; ++nt)
                    out[(size_t)rr * DD + nt * 16 + (lane & 15)] = acc[nt][r];
            }
        }
    }
}

// ---------------- pooling: grid-wide partials + finalize ----------------
__global__ void pool_partial(const float* __restrict__ x, const int* __restrict__ batch,
                             float* __restrict__ sums, int n) {
    const int lane = threadIdx.x & 63;
    const int wv   = (int)((blockIdx.x * blockDim.x + threadIdx.x) >> 6);
    const int nwv  = (int)((gridDim.x * blockDim.x) >> 6);
    const int chunk = (n + nwv - 1) / nwv;
    const int start = wv * chunk;
    if (start >= n) return;
    const int end = min(start + chunk, n);

    int g = batch[start];
    float acc = 0.f;
    for (int nd = start; nd < end; ++nd) {
        const int bg = batch[nd];
        if (bg != g) {
            atomicAdd(&sums[(size_t)g * DD + lane], acc);
            acc = 0.f;
            g = bg;
        }
        acc += x[(size_t)nd * DD + lane];
    }
    atomicAdd(&sums[(size_t)g * DD + lane], acc);
}

__global__ void pool_final(const float* __restrict__ sums, const int* __restrict__ batch,
                           float* __restrict__ out, int n) {
    const int g = blockIdx.x;
    const int t = threadIdx.x;  // 64 threads
    int lo = 0, hi = n;
    while (lo < hi) { int m = (lo + hi) >> 1; if (batch[m] < g) lo = m + 1; else hi = m; }
    const int st = lo;
    lo = 0; hi = n;
    while (lo < hi) { int m = (lo + hi) >> 1; if (batch[m] < g + 1) lo = m + 1; else hi = m; }
    const int c = lo - st;
    out[(size_t)g * DD + t] = sums[(size_t)g * DD + t] / (float)((c > 0) ? c : 1);
}

extern "C" void kernel_launch(void* const* d_in, const int* in_sizes, int n_in,
                              void* d_out, int out_size, void* d_ws, size_t ws_size,
                              hipStream_t stream) {
    const float* x     = (const float*)d_in[0];
    const int*   ei    = (const int*)d_in[1];
    const int*   batch = (const int*)d_in[2];
    const float* Wl    = (const float*)d_in[3];
    const float* bl    = (const float*)d_in[4];
    const float* Wr    = (const float*)d_in[5];

    const int N = in_sizes[0] / DD;
    const int E = in_sizes[1] / 2;
    const int L = in_sizes[3] / (DD * DD);
    const int G = out_size / DD;

    const int* src = ei;        // edge_index[0]
    const int* dst = ei + E;    // edge_index[1]

    char* ws = (char*)d_ws;
    size_t off = 0;
    auto alloc = [&](size_t bytes) -> char* {
        char* p = ws + off;
        off += (bytes + 255) & ~(size_t)255;
        return p;
    };
    int*      deg    = (int*)alloc((size_t)N * 4);
    int*      offs   = (int*)alloc((size_t)(N + 1) * 4);
    int*      cursor = (int*)alloc((size_t)N * 4);
    int*      adj    = (int*)alloc((size_t)E * 4);
    int*      bsum   = (int*)alloc(1024 * 4);
    float*    b0     = (float*)alloc((size_t)N * DD * 4);
    float*    b1     = (float*)alloc((size_t)N * DD * 4);
    float*    aggbuf = (float*)alloc((size_t)N * DD * 4);
    unsigned* Bp     = (unsigned*)alloc((size_t)L * 2 * 16 * 64 * 4 * 4);
    float*    sums   = (float*)alloc((size_t)G * DD * 4);

    // ---- CSR build (graph reused by all layers) ----
    hipMemsetAsync(deg, 0, (size_t)N * 4, stream);
    count_deg<<<(E + 255) / 256, 256, 0, stream>>>(dst, deg, E);
    const int nb = (N + 1023) / 1024;
    scan1<<<nb, 1024, 0, stream>>>(deg, offs, bsum, N);
    scan2<<<1, 1024, 0, stream>>>(bsum, nb);
    scan3<<<nb, 1024, 0, stream>>>(offs, bsum, N);
    hipMemcpyAsync(cursor, offs, (size_t)N * 4, hipMemcpyDeviceToDevice, stream);
    fill_adj<<<(E + 255) / 256, 256, 0, stream>>>(src, dst, cursor, adj, E);

    // ---- pack W into MFMA fragment layout (all layers) ----
    pack_B<<<(L * 16 * 64 + 255) / 256, 256, 0, stream>>>(Wl, Wr, Bp, L);

    // ---- layers (ping-pong) ----
    const int agg_blocks = (N * 16 + 255) / 256;
    const float* cur = x;
    float* bufs[2] = {b0, b1};
    for (int l = 0; l < L; ++l) {
        float* outb = bufs[l & 1];
        aggregate<<<agg_blocks, 256, 0, stream>>>(cur, aggbuf, offs, adj, N);
        mfma_gemm<<<640, 256, 0, stream>>>(aggbuf, cur, outb,
                                           Bp + (size_t)l * 2 * 16 * 64 * 4,
                                           bl + (size_t)l * DD, N);
        cur = outb;
    }

    // ---- per-graph mean pool: partials + finalize ----
    hipMemsetAsync(sums, 0, (size_t)G * DD * 4, stream);
    pool_partial<<<256, 256, 0, stream>>>(cur, batch, sums, N);
    pool_final<<<G, DD, 0, stream>>>(sums, batch, (float*)d_out, N);
}